// Round 1
// baseline (1993.780 us; speedup 1.0000x reference)
//
#include <hip/hip_runtime.h>
#include <math.h>

#define MAX_LEN 4096
#define D_MODEL 768
#define PE_DIM 65
#define MLP_W 64
#define NBATCH 4
#define D3 2304               // (ORDER+1)*D_MODEL
#define ROWS (NBATCH*MAX_LEN) // 16384

// ---------------------------------------------------------------------------
// K1: filter MLP + decay -> hT (D_MODEL x MAX_LEN, d-major)
// ---------------------------------------------------------------------------
__global__ void filter_kernel(const float* __restrict__ z,
                              const float* __restrict__ fin_W,
                              const float* __restrict__ fin_b,
                              const float* __restrict__ freq,
                              const float* __restrict__ mid_W,
                              const float* __restrict__ mid_b,
                              const float* __restrict__ fout_W,
                              float* __restrict__ hT)
{
    int t = blockIdx.x;
    int j = threadIdx.x;  // 0..63
    __shared__ float zrow[PE_DIM];
    __shared__ float k1[MLP_W];
    __shared__ float k2[MLP_W];
    __shared__ float k3[MLP_W];
    for (int i = j; i < PE_DIM; i += MLP_W) zrow[i] = z[t*PE_DIM + i];
    __syncthreads();
    float fj = freq[j];
    float acc = fin_b[j];
    for (int i = 0; i < PE_DIM; ++i) acc += zrow[i]*fin_W[i*MLP_W + j];
    k1[j] = sinf(fj*acc);
    __syncthreads();
    acc = mid_b[j];
    for (int i = 0; i < MLP_W; ++i) acc += k1[i]*mid_W[i*MLP_W + j];
    k2[j] = sinf(fj*acc);
    __syncthreads();
    acc = mid_b[MLP_W + j];
    for (int i = 0; i < MLP_W; ++i) acc += k2[i]*mid_W[MLP_W*MLP_W + i*MLP_W + j];
    k3[j] = sinf(fj*acc);
    __syncthreads();
    const float MIND = -3.0701134573253944f;   // ln(0.01)/1.5
    const float MAXD = -15.350567286626972f;   // ln(0.01)/0.3
    float tt = (float)t * (1.0f/(float)(MAX_LEN-1));
    for (int m = 0; m < D_MODEL/MLP_W; ++m) {
        int d = j + MLP_W*m;
        float a = 0.f;
        for (int i = 0; i < MLP_W; ++i) a += k3[i]*fout_W[i*D_MODEL + d];
        float delta = MIND + (MAXD-MIND)*((float)d*(1.0f/(float)(D_MODEL-1)));
        float dec = expf(-tt*fabsf(delta));
        hT[(size_t)d*MAX_LEN + t] = a*dec;
    }
}

// ---------------------------------------------------------------------------
// K2/K6: C[M,N] = A[M,K] @ B[K,N] + bias[N]   (fp32 vector GEMM, 128x128x16)
// ---------------------------------------------------------------------------
#define BM 128
#define BN 128
#define BK 16

__launch_bounds__(256)
__global__ void gemm_bias_kernel(const float* __restrict__ A,
                                 const float* __restrict__ B,
                                 const float* __restrict__ bias,
                                 float* __restrict__ C,
                                 int M, int N, int K)
{
    __shared__ float As[BK][BM+4];   // +4 pad: staging writes 2-way max
    __shared__ float Bs[BK][BN];
    int tid = threadIdx.x;
    int tx = tid & 15, ty = tid >> 4;
    int n0 = blockIdx.x * BN, m0 = blockIdx.y * BM;
    float acc[8][8];
    #pragma unroll
    for (int i = 0; i < 8; ++i)
        #pragma unroll
        for (int j = 0; j < 8; ++j) acc[i][j] = 0.f;
    int arow = tid >> 2, akq = (tid & 3)*4;
    int brow = tid >> 5, bcol = (tid & 31)*4;
    for (int k0 = 0; k0 < K; k0 += BK) {
        #pragma unroll
        for (int p = 0; p < 2; ++p) {
            float4 av = *(const float4*)&A[(size_t)(m0+arow+64*p)*K + k0 + akq];
            As[akq+0][arow+64*p] = av.x;
            As[akq+1][arow+64*p] = av.y;
            As[akq+2][arow+64*p] = av.z;
            As[akq+3][arow+64*p] = av.w;
        }
        #pragma unroll
        for (int p = 0; p < 2; ++p) {
            *(float4*)&Bs[brow+8*p][bcol] =
                *(const float4*)&B[(size_t)(k0+brow+8*p)*N + n0 + bcol];
        }
        __syncthreads();
        #pragma unroll
        for (int k = 0; k < BK; ++k) {
            float a[8], b[8];
            *(float4*)&a[0] = *(const float4*)&As[k][ty*8];
            *(float4*)&a[4] = *(const float4*)&As[k][ty*8+4];
            *(float4*)&b[0] = *(const float4*)&Bs[k][tx*8];
            *(float4*)&b[4] = *(const float4*)&Bs[k][tx*8+4];
            #pragma unroll
            for (int i = 0; i < 8; ++i)
                #pragma unroll
                for (int j = 0; j < 8; ++j)
                    acc[i][j] += a[i]*b[j];
        }
        __syncthreads();
    }
    float bv[8];
    #pragma unroll
    for (int j = 0; j < 8; ++j) bv[j] = bias[n0 + tx*8 + j];
    #pragma unroll
    for (int i = 0; i < 8; ++i) {
        size_t row = (size_t)(m0 + ty*8 + i)*N + n0 + tx*8;
        float4 o0 = make_float4(acc[i][0]+bv[0], acc[i][1]+bv[1], acc[i][2]+bv[2], acc[i][3]+bv[3]);
        float4 o1 = make_float4(acc[i][4]+bv[4], acc[i][5]+bv[5], acc[i][6]+bv[6], acc[i][7]+bv[7]);
        *(float4*)&C[row]   = o0;
        *(float4*)&C[row+4] = o1;
    }
}

// ---------------------------------------------------------------------------
// K3: short conv (width 3, causal) + split + seq=x0*v, gate=x1
//   up: (B*L, 2304) -> seqT: (B, 768, L) [transposed via LDS], gate: (B*L, 768)
// ---------------------------------------------------------------------------
__global__ void convprep_kernel(const float* __restrict__ up,
                                const float* __restrict__ conv_W,
                                const float* __restrict__ conv_b,
                                float* __restrict__ seqT,
                                float* __restrict__ gate)
{
    __shared__ float sb[64][65];
    int d0 = blockIdx.x * 64;
    int t0 = blockIdx.y * 64;
    int b  = blockIdx.z;
    int tid = threadIdx.x;
    #pragma unroll
    for (int i = 0; i < 16; ++i) {
        int idx = tid + 256*i;          // 0..4095
        int trow = idx >> 6, dcol = idx & 63;
        int t = t0 + trow;
        int d = d0 + dcol;
        size_t r = ((size_t)b*MAX_LEN + t)*D3;
        float uc[3];
        #pragma unroll
        for (int g = 0; g < 3; ++g) {
            int c = d + g*D_MODEL;
            float u0 = up[r + c];                                   // up[t]
            float u1 = (t >= 1) ? up[r - D3 + c]   : 0.f;           // up[t-1]
            float u2 = (t >= 2) ? up[r - 2*D3 + c] : 0.f;           // up[t-2]
            uc[g] = conv_W[c]*u2 + conv_W[D3 + c]*u1 + conv_W[2*D3 + c]*u0 + conv_b[c];
        }
        sb[trow][dcol] = uc[0]*uc[2];                               // seq = x0 * v
        gate[((size_t)b*MAX_LEN + t)*D_MODEL + d] = uc[1];          // x1
    }
    __syncthreads();
    #pragma unroll
    for (int i = 0; i < 16; ++i) {
        int idx = tid + 256*i;
        int drow = idx >> 6, tcol = idx & 63;
        seqT[((size_t)b*D_MODEL + d0 + drow)*MAX_LEN + t0 + tcol] = sb[tcol][drow];
    }
}

// ---------------------------------------------------------------------------
// K4: long causal depthwise conv, one workgroup per (b,d), in-place on seqT.
//   y[t] = sum_{s<=t} seq[s]*h[t-s] + seq[t]*filt_bias[d]
// LDS: sbuf (seq, 16KB) + hbuf (zero-padded filter, quad-swizzled, 36.9KB).
// Thread tid owns outputs [16*tid, 16*tid+16); 16-wide s-blocks; H window
// read as 8 aligned ds_read_b128 (quad swizzle phys_q=q+(q>>3) kills the
// lane-stride-64B bank conflicts).
// ---------------------------------------------------------------------------
__global__ void longconv_kernel(float* seq_io,                    // (B,768,L) in/out
                                const float* __restrict__ hT,    // (768,L)
                                const float* __restrict__ filt_bias)
{
    __shared__ float sbuf[MAX_LEN];          // 4096 floats
    __shared__ float hbuf[2304*4];           // 2304 quads (2048 logical + swizzle pad)
    int bd  = blockIdx.x;                    // b*768 + d
    int d   = bd % D_MODEL;
    int tid = threadIdx.x;

    float* src = seq_io + (size_t)bd*MAX_LEN;
    #pragma unroll
    for (int q = tid; q < MAX_LEN/4; q += 256)
        *(float4*)&sbuf[q*4] = *(const float4*)&src[q*4];
    // zero entire swizzled filter buffer (covers the j<0 region)
    float4 z4 = make_float4(0.f, 0.f, 0.f, 0.f);
    #pragma unroll
    for (int q = tid; q < 2304; q += 256)
        *(float4*)&hbuf[q*4] = z4;
    __syncthreads();
    // logical hpad[L] = (L>=4096) ? h[L-4096] : 0 ; quad q = L/4, phys = q+(q>>3)
    const float* hsrc = hT + (size_t)d*MAX_LEN;
    #pragma unroll
    for (int tq = tid; tq < MAX_LEN/4; tq += 256) {
        int q = 1024 + tq;
        int pq = q + (q >> 3);
        *(float4*)&hbuf[pq*4] = *(const float4*)&hsrc[tq*4];
    }
    __syncthreads();

    int t0 = tid*16;
    float acc[16];
    #pragma unroll
    for (int i = 0; i < 16; ++i) acc[i] = 0.f;

    for (int sblk = 0; sblk <= tid; ++sblk) {
        int s0 = sblk*16;
        // S block (uniform address -> broadcast reads)
        float Sf[16];
        #pragma unroll
        for (int q2 = 0; q2 < 4; ++q2) {
            float4 sv = *(const float4*)&sbuf[s0 + 4*q2];
            Sf[4*q2+0] = sv.x; Sf[4*q2+1] = sv.y; Sf[4*q2+2] = sv.z; Sf[4*q2+3] = sv.w;
        }
        // H window: logical [Lb, Lb+31], Lb = 4096 + t0 - s0 - 16 (16-aligned)
        int qb = 1024 + 4*tid - 4*sblk - 4;
        float Hf[32];
        #pragma unroll
        for (int k2 = 0; k2 < 8; ++k2) {
            int q = qb + k2;
            int pq = q + (q >> 3);
            float4 hv = *(const float4*)&hbuf[pq*4];
            Hf[4*k2+0] = hv.x; Hf[4*k2+1] = hv.y; Hf[4*k2+2] = hv.z; Hf[4*k2+3] = hv.w;
        }
        #pragma unroll
        for (int si = 0; si < 16; ++si)
            #pragma unroll
            for (int i = 0; i < 16; ++i)
                acc[i] += Sf[si] * Hf[i - si + 16];
    }

    float fb = filt_bias[d];
    #pragma unroll
    for (int i = 0; i < 16; ++i) acc[i] += sbuf[t0 + i]*fb;

    float* dst = src;
    #pragma unroll
    for (int q2 = 0; q2 < 4; ++q2) {
        float4 ov = make_float4(acc[4*q2+0], acc[4*q2+1], acc[4*q2+2], acc[4*q2+3]);
        *(float4*)&dst[t0 + 4*q2] = ov;
    }
}

// ---------------------------------------------------------------------------
// K5: Afin[b*L+t, d] = yT[b,d,t] * gate[b*L+t, d]   (transpose via LDS)
// ---------------------------------------------------------------------------
__global__ void gatemul_kernel(const float* __restrict__ yT,
                               const float* __restrict__ gate,
                               float* __restrict__ Afin)
{
    __shared__ float tb[64][65];
    int d0 = blockIdx.x * 64;
    int t0 = blockIdx.y * 64;
    int b  = blockIdx.z;
    int tid = threadIdx.x;
    #pragma unroll
    for (int i = 0; i < 16; ++i) {
        int idx = tid + 256*i;
        int drow = idx >> 6, tcol = idx & 63;
        tb[drow][tcol] = yT[((size_t)b*D_MODEL + d0 + drow)*MAX_LEN + t0 + tcol];
    }
    __syncthreads();
    #pragma unroll
    for (int i = 0; i < 16; ++i) {
        int idx = tid + 256*i;
        int trow = idx >> 6, dcol = idx & 63;
        size_t r = ((size_t)b*MAX_LEN + t0 + trow)*D_MODEL + d0 + dcol;
        Afin[r] = tb[dcol][trow] * gate[r];
    }
}

// ---------------------------------------------------------------------------
extern "C" void kernel_launch(void* const* d_in, const int* in_sizes, int n_in,
                              void* d_out, int out_size, void* d_ws, size_t ws_size,
                              hipStream_t stream)
{
    (void)in_sizes; (void)n_in; (void)out_size; (void)ws_size;
    const float* u      = (const float*)d_in[0];
    const float* z      = (const float*)d_in[1];
    const float* fin_W  = (const float*)d_in[2];
    const float* fin_b  = (const float*)d_in[3];
    const float* freq   = (const float*)d_in[4];
    const float* mid_W  = (const float*)d_in[5];
    const float* mid_b  = (const float*)d_in[6];
    const float* fout_W = (const float*)d_in[7];
    const float* proj_W = (const float*)d_in[8];
    const float* proj_b = (const float*)d_in[9];
    const float* conv_W = (const float*)d_in[10];
    const float* conv_b = (const float*)d_in[11];
    const float* fbias  = (const float*)d_in[12];
    const float* out_W  = (const float*)d_in[13];
    const float* out_b  = (const float*)d_in[14];
    float* out = (float*)d_out;

    // ws layout (floats): hT | up(reused as Afin) | seqT(in-place y) | gate
    float* ws   = (float*)d_ws;
    float* hT   = ws;                                        //   768*4096 =  3.15M
    float* up   = hT   + (size_t)D_MODEL*MAX_LEN;            // 16384*2304 = 37.75M
    float* seqT = up   + (size_t)ROWS*D3;                    //  4*768*4096= 12.58M
    float* gate = seqT + (size_t)NBATCH*D_MODEL*MAX_LEN;     // 16384*768  = 12.58M
    float* Afin = up;   // up is dead after convprep         // total ~264 MB

    filter_kernel<<<MAX_LEN, MLP_W, 0, stream>>>(z, fin_W, fin_b, freq,
                                                 mid_W, mid_b, fout_W, hT);
    gemm_bias_kernel<<<dim3(D3/BN, ROWS/BM), 256, 0, stream>>>(
        u, proj_W, proj_b, up, ROWS, D3, D_MODEL);
    convprep_kernel<<<dim3(D_MODEL/64, MAX_LEN/64, NBATCH), 256, 0, stream>>>(
        up, conv_W, conv_b, seqT, gate);
    longconv_kernel<<<NBATCH*D_MODEL, 256, 0, stream>>>(seqT, hT, fbias);
    gatemul_kernel<<<dim3(D_MODEL/64, MAX_LEN/64, NBATCH), 256, 0, stream>>>(
        seqT, gate, Afin);
    gemm_bias_kernel<<<dim3(D_MODEL/BN, ROWS/BM), 256, 0, stream>>>(
        Afin, out_W, out_b, out, ROWS, D_MODEL, D_MODEL);
}

// Round 2
// 1211.387 us; speedup vs baseline: 1.6459x; 1.6459x over previous
//
#include <hip/hip_runtime.h>
#include <math.h>

#define MAX_LEN 4096
#define D_MODEL 768
#define PE_DIM 65
#define MLP_W 64
#define NBATCH 4
#define D3 2304               // (ORDER+1)*D_MODEL
#define ROWS (NBATCH*MAX_LEN) // 16384

typedef unsigned short u16;
typedef unsigned int u32;
typedef float f4 __attribute__((ext_vector_type(4)));
typedef __bf16 bf16x8 __attribute__((ext_vector_type(8)));
typedef float f32x4 __attribute__((ext_vector_type(4)));

__device__ inline u16 f2bf(float x) {
    u32 u = __float_as_uint(x);
    u += 0x7fffu + ((u >> 16) & 1u);   // round-to-nearest-even
    return (u16)(u >> 16);
}

// ---------------------------------------------------------------------------
// K1: filter MLP + decay -> hT (D_MODEL x MAX_LEN, d-major)
// ---------------------------------------------------------------------------
__global__ void filter_kernel(const float* __restrict__ z,
                              const float* __restrict__ fin_W,
                              const float* __restrict__ fin_b,
                              const float* __restrict__ freq,
                              const float* __restrict__ mid_W,
                              const float* __restrict__ mid_b,
                              const float* __restrict__ fout_W,
                              float* __restrict__ hT)
{
    int t = blockIdx.x;
    int j = threadIdx.x;  // 0..63
    __shared__ float zrow[PE_DIM];
    __shared__ float k1[MLP_W];
    __shared__ float k2[MLP_W];
    __shared__ float k3[MLP_W];
    for (int i = j; i < PE_DIM; i += MLP_W) zrow[i] = z[t*PE_DIM + i];
    __syncthreads();
    float fj = freq[j];
    float acc = fin_b[j];
    for (int i = 0; i < PE_DIM; ++i) acc += zrow[i]*fin_W[i*MLP_W + j];
    k1[j] = sinf(fj*acc);
    __syncthreads();
    acc = mid_b[j];
    for (int i = 0; i < MLP_W; ++i) acc += k1[i]*mid_W[i*MLP_W + j];
    k2[j] = sinf(fj*acc);
    __syncthreads();
    acc = mid_b[MLP_W + j];
    for (int i = 0; i < MLP_W; ++i) acc += k2[i]*mid_W[MLP_W*MLP_W + i*MLP_W + j];
    k3[j] = sinf(fj*acc);
    __syncthreads();
    const float MIND = -3.0701134573253944f;   // ln(0.01)/1.5
    const float MAXD = -15.350567286626972f;   // ln(0.01)/0.3
    float tt = (float)t * (1.0f/(float)(MAX_LEN-1));
    for (int m = 0; m < D_MODEL/MLP_W; ++m) {
        int d = j + MLP_W*m;
        float a = 0.f;
        for (int i = 0; i < MLP_W; ++i) a += k3[i]*fout_W[i*D_MODEL + d];
        float delta = MIND + (MAXD-MIND)*((float)d*(1.0f/(float)(D_MODEL-1)));
        float dec = expf(-tt*fabsf(delta));
        hT[(size_t)d*MAX_LEN + t] = a*dec;
    }
}

// ---------------------------------------------------------------------------
// cast fp32 -> bf16 (elementwise, 8/thread)
// ---------------------------------------------------------------------------
__global__ void cast_bf16_kernel(const float* __restrict__ src,
                                 u16* __restrict__ dst, int n)
{
    int i = (blockIdx.x*256 + threadIdx.x)*8;
    if (i + 7 >= n) {
        for (int j = i; j < n; ++j) dst[j] = f2bf(src[j]);
        return;
    }
    float4 a = *(const float4*)(src + i);
    float4 b = *(const float4*)(src + i + 4);
    uint4 o;
    o.x = (u32)f2bf(a.x) | ((u32)f2bf(a.y) << 16);
    o.y = (u32)f2bf(a.z) | ((u32)f2bf(a.w) << 16);
    o.z = (u32)f2bf(b.x) | ((u32)f2bf(b.y) << 16);
    o.w = (u32)f2bf(b.z) | ((u32)f2bf(b.w) << 16);
    *(uint4*)(dst + i) = o;
}

// ---------------------------------------------------------------------------
// transpose + cast: src (R x C fp32) -> dst (C x R bf16)
// ---------------------------------------------------------------------------
__global__ void transpose_cast_kernel(const float* __restrict__ src,
                                      u16* __restrict__ dst, int R, int C)
{
    __shared__ u16 tile[64][65];
    int c0 = blockIdx.x*64, r0 = blockIdx.y*64;
    int tid = threadIdx.x;
    #pragma unroll
    for (int p = 0; p < 16; ++p) {
        int idx = tid + 256*p;
        int rr = idx >> 6, cc = idx & 63;
        tile[rr][cc] = f2bf(src[(size_t)(r0+rr)*C + c0 + cc]);
    }
    __syncthreads();
    #pragma unroll
    for (int p = 0; p < 16; ++p) {
        int idx = tid + 256*p;
        int cr = idx >> 6, rc = idx & 63;
        dst[(size_t)(c0+cr)*R + r0 + rc] = tile[rc][cr];
    }
}

// ---------------------------------------------------------------------------
// K2/K6: C[M,N] = A[M,K]bf16 @ Bt[N,K]bf16 + bias  (MFMA 16x16x32, 128x128 tile)
// LDS rows padded to 40 u16 (80B) -> conflict-free b128 frag reads.
// ---------------------------------------------------------------------------
__launch_bounds__(256)
__global__ void gemm_mfma_kernel(const u16* __restrict__ A,   // M x K
                                 const u16* __restrict__ Bt,  // N x K
                                 const float* __restrict__ bias,
                                 float* __restrict__ C,
                                 int M, int N, int K)
{
    __shared__ __align__(16) u16 As[128*40];
    __shared__ __align__(16) u16 Bs[128*40];
    int tid = threadIdx.x;
    int lane = tid & 63, w = tid >> 6;
    int wm = (w >> 1)*64, wn = (w & 1)*64;
    int lrow = lane & 15, lch = lane >> 4;
    int m0 = blockIdx.y * 128, n0 = blockIdx.x * 128;

    int srow = tid >> 1, sc = (tid & 1)*16;     // each thread: 16 u16 A + 16 u16 B
    const u16* Ag = A + (size_t)(m0 + srow)*K + sc;
    const u16* Bg = Bt + (size_t)(n0 + srow)*K + sc;
    int soff = srow*40 + sc;

    f32x4 acc[4][4];
    #pragma unroll
    for (int i = 0; i < 4; ++i)
        #pragma unroll
        for (int j = 0; j < 4; ++j)
            acc[i][j] = (f32x4){0.f,0.f,0.f,0.f};

    for (int k0 = 0; k0 < K; k0 += 32) {
        float4 a0 = *(const float4*)(Ag + k0);
        float4 a1 = *(const float4*)(Ag + k0 + 8);
        float4 b0 = *(const float4*)(Bg + k0);
        float4 b1 = *(const float4*)(Bg + k0 + 8);
        __syncthreads();
        *(float4*)&As[soff]   = a0;
        *(float4*)&As[soff+8] = a1;
        *(float4*)&Bs[soff]   = b0;
        *(float4*)&Bs[soff+8] = b1;
        __syncthreads();
        bf16x8 af[4], bfr[4];
        #pragma unroll
        for (int i = 0; i < 4; ++i) {
            af[i]  = *(const bf16x8*)&As[(wm + i*16 + lrow)*40 + lch*8];
            bfr[i] = *(const bf16x8*)&Bs[(wn + i*16 + lrow)*40 + lch*8];
        }
        #pragma unroll
        for (int mt = 0; mt < 4; ++mt)
            #pragma unroll
            for (int nt = 0; nt < 4; ++nt)
                acc[mt][nt] = __builtin_amdgcn_mfma_f32_16x16x32_bf16(
                    af[mt], bfr[nt], acc[mt][nt], 0, 0, 0);
    }
    #pragma unroll
    for (int nt = 0; nt < 4; ++nt) {
        int n = n0 + wn + nt*16 + lrow;
        float bv = bias[n];
        #pragma unroll
        for (int mt = 0; mt < 4; ++mt) {
            int m = m0 + wm + mt*16 + lch*4;
            #pragma unroll
            for (int r = 0; r < 4; ++r)
                C[(size_t)(m + r)*N + n] = acc[mt][nt][r] + bv;
        }
    }
}

// ---------------------------------------------------------------------------
// K3: short conv (width 3, causal) + split + seq=x0*v, gate=x1
// ---------------------------------------------------------------------------
__global__ void convprep_kernel(const float* __restrict__ up,
                                const float* __restrict__ conv_W,
                                const float* __restrict__ conv_b,
                                float* __restrict__ seqT,
                                float* __restrict__ gate)
{
    __shared__ float sb[64][65];
    int d0 = blockIdx.x * 64;
    int t0 = blockIdx.y * 64;
    int b  = blockIdx.z;
    int tid = threadIdx.x;
    #pragma unroll
    for (int i = 0; i < 16; ++i) {
        int idx = tid + 256*i;
        int trow = idx >> 6, dcol = idx & 63;
        int t = t0 + trow;
        int d = d0 + dcol;
        size_t r = ((size_t)b*MAX_LEN + t)*D3;
        float uc[3];
        #pragma unroll
        for (int g = 0; g < 3; ++g) {
            int c = d + g*D_MODEL;
            float u0 = up[r + c];
            float u1 = (t >= 1) ? up[r - D3 + c]   : 0.f;
            float u2 = (t >= 2) ? up[r - 2*D3 + c] : 0.f;
            uc[g] = conv_W[c]*u2 + conv_W[D3 + c]*u1 + conv_W[2*D3 + c]*u0 + conv_b[c];
        }
        sb[trow][dcol] = uc[0]*uc[2];
        gate[((size_t)b*MAX_LEN + t)*D_MODEL + d] = uc[1];
    }
    __syncthreads();
    #pragma unroll
    for (int i = 0; i < 16; ++i) {
        int idx = tid + 256*i;
        int drow = idx >> 6, tcol = idx & 63;
        seqT[((size_t)b*D_MODEL + d0 + drow)*MAX_LEN + t0 + tcol] = sb[tcol][drow];
    }
}

// ---------------------------------------------------------------------------
// K4: long causal depthwise conv, one workgroup per (b,d), in-place on seqT.
// hbuf: logical float x in [0,4128): x<32 -> 0, else h[x-32]; quad-swizzled
// pq = q + (q>>3). Thread tid owns outputs [16*tid,16*tid+16).
// Register residency of S/H forced via asm pins.
// ---------------------------------------------------------------------------
__global__ void longconv_kernel(float* seq_io,
                                const float* __restrict__ hT,
                                const float* __restrict__ filt_bias)
{
    __shared__ float sbuf[MAX_LEN];          // 16 KB
    __shared__ float hbuf[1164*4];           // 18.6 KB (1032 logical quads + swizzle)
    int bd  = blockIdx.x;
    int d   = bd % D_MODEL;
    int tid = threadIdx.x;

    float* src = seq_io + (size_t)bd*MAX_LEN;
    for (int q = tid; q < 1024; q += 256)
        *(f4*)&sbuf[q*4] = *(const f4*)&src[q*4];
    f4 z4 = {0.f,0.f,0.f,0.f};
    for (int q = tid; q < 1164; q += 256)
        *(f4*)&hbuf[q*4] = z4;
    __syncthreads();
    const float* hsrc = hT + (size_t)d*MAX_LEN;
    for (int tq = tid; tq < 1024; tq += 256) {
        int q = 8 + tq;                      // logical quad (float 32 + 4*tq)
        int pq = q + (q >> 3);
        *(f4*)&hbuf[pq*4] = *(const f4*)&hsrc[tq*4];
    }
    __syncthreads();

    int t0 = tid*16;
    float acc[16];
    #pragma unroll
    for (int i = 0; i < 16; ++i) acc[i] = 0.f;

    for (int sblk = 0; sblk <= tid; ++sblk) {
        int s0 = sblk*16;
        f4 s0v = *(const f4*)&sbuf[s0];
        f4 s1v = *(const f4*)&sbuf[s0+4];
        f4 s2v = *(const f4*)&sbuf[s0+8];
        f4 s3v = *(const f4*)&sbuf[s0+12];
        int qb = 4*(tid - sblk) + 4;         // logical quad base of H window
        f4 h0,h1,h2,h3,h4,h5,h6,h7;
        { int q=qb+0; h0 = *(const f4*)&hbuf[(q+(q>>3))*4]; }
        { int q=qb+1; h1 = *(const f4*)&hbuf[(q+(q>>3))*4]; }
        { int q=qb+2; h2 = *(const f4*)&hbuf[(q+(q>>3))*4]; }
        { int q=qb+3; h3 = *(const f4*)&hbuf[(q+(q>>3))*4]; }
        { int q=qb+4; h4 = *(const f4*)&hbuf[(q+(q>>3))*4]; }
        { int q=qb+5; h5 = *(const f4*)&hbuf[(q+(q>>3))*4]; }
        { int q=qb+6; h6 = *(const f4*)&hbuf[(q+(q>>3))*4]; }
        { int q=qb+7; h7 = *(const f4*)&hbuf[(q+(q>>3))*4]; }
        asm volatile("" : "+v"(h0), "+v"(h1), "+v"(h2), "+v"(h3));
        asm volatile("" : "+v"(h4), "+v"(h5), "+v"(h6), "+v"(h7));
        asm volatile("" : "+v"(s0v), "+v"(s1v), "+v"(s2v), "+v"(s3v));
        float S[16] = {s0v.x,s0v.y,s0v.z,s0v.w, s1v.x,s1v.y,s1v.z,s1v.w,
                       s2v.x,s2v.y,s2v.z,s2v.w, s3v.x,s3v.y,s3v.z,s3v.w};
        float H[32] = {h0.x,h0.y,h0.z,h0.w, h1.x,h1.y,h1.z,h1.w,
                       h2.x,h2.y,h2.z,h2.w, h3.x,h3.y,h3.z,h3.w,
                       h4.x,h4.y,h4.z,h4.w, h5.x,h5.y,h5.z,h5.w,
                       h6.x,h6.y,h6.z,h6.w, h7.x,h7.y,h7.z,h7.w};
        #define SIB(SI) { float sv = S[SI]; _Pragma("unroll") \
            for (int i = 0; i < 16; ++i) acc[i] += sv * H[i - (SI) + 16]; }
        SIB(0)  SIB(1)  SIB(2)  SIB(3)  SIB(4)  SIB(5)  SIB(6)  SIB(7)
        SIB(8)  SIB(9)  SIB(10) SIB(11) SIB(12) SIB(13) SIB(14) SIB(15)
        #undef SIB
    }

    float fb = filt_bias[d];
    #pragma unroll
    for (int i = 0; i < 16; ++i) acc[i] += sbuf[t0 + i]*fb;

    #pragma unroll
    for (int q2 = 0; q2 < 4; ++q2) {
        f4 ov = {acc[4*q2+0], acc[4*q2+1], acc[4*q2+2], acc[4*q2+3]};
        *(f4*)&src[t0 + 4*q2] = ov;
    }
}

// ---------------------------------------------------------------------------
// K5: Afin(bf16)[b*L+t, d] = yT[b,d,t] * gate[b*L+t, d]
// ---------------------------------------------------------------------------
__global__ void gatemul_kernel(const float* __restrict__ yT,
                               const float* __restrict__ gate,
                               u16* __restrict__ Afin)
{
    __shared__ float tb[64][65];
    int d0 = blockIdx.x * 64;
    int t0 = blockIdx.y * 64;
    int b  = blockIdx.z;
    int tid = threadIdx.x;
    #pragma unroll
    for (int i = 0; i < 16; ++i) {
        int idx = tid + 256*i;
        int drow = idx >> 6, tcol = idx & 63;
        tb[drow][tcol] = yT[((size_t)b*D_MODEL + d0 + drow)*MAX_LEN + t0 + tcol];
    }
    __syncthreads();
    #pragma unroll
    for (int i = 0; i < 16; ++i) {
        int idx = tid + 256*i;
        int trow = idx >> 6, dcol = idx & 63;
        size_t r = ((size_t)b*MAX_LEN + t0 + trow)*D_MODEL + d0 + dcol;
        Afin[r] = f2bf(tb[dcol][trow] * gate[r]);
    }
}

// ---------------------------------------------------------------------------
extern "C" void kernel_launch(void* const* d_in, const int* in_sizes, int n_in,
                              void* d_out, int out_size, void* d_ws, size_t ws_size,
                              hipStream_t stream)
{
    (void)in_sizes; (void)n_in; (void)out_size; (void)ws_size;
    const float* u      = (const float*)d_in[0];
    const float* z      = (const float*)d_in[1];
    const float* fin_W  = (const float*)d_in[2];
    const float* fin_b  = (const float*)d_in[3];
    const float* freq   = (const float*)d_in[4];
    const float* mid_W  = (const float*)d_in[5];
    const float* mid_b  = (const float*)d_in[6];
    const float* fout_W = (const float*)d_in[7];
    const float* proj_W = (const float*)d_in[8];
    const float* proj_b = (const float*)d_in[9];
    const float* conv_W = (const float*)d_in[10];
    const float* conv_b = (const float*)d_in[11];
    const float* fbias  = (const float*)d_in[12];
    const float* out_W  = (const float*)d_in[13];
    const float* out_b  = (const float*)d_in[14];
    float* out = (float*)d_out;

    // ws layout (floats): hT | up | seqR | gateR   (total 66.05M f = 264 MB)
    float* ws    = (float*)d_ws;
    float* hT    = ws;                                   //  3,145,728 f
    float* up    = hT   + (size_t)D_MODEL*MAX_LEN;       // 37,748,736 f
    float* seqR  = up   + (size_t)ROWS*D3;               // 12,582,912 f
    float* gateR = seqR + (size_t)NBATCH*D_MODEL*MAX_LEN;// 12,582,912 f
    // bf16 aliases in regions that are dead at time of use:
    u16* Abf    = (u16*)seqR;                 // u bf16 (dead after GEMM1; convprep overwrites)
    u16* BpT1   = (u16*)gateR;                // proj_W^T bf16 (dead after GEMM1)
    u16* Afinbf = (u16*)up;                   // up fp32 dead after convprep
    u16* BpT2   = (u16*)(up + (size_t)20*1024*1024);  // out_W^T bf16, in dead up region
    float* seqT = seqR;
    float* gate = gateR;

    filter_kernel<<<MAX_LEN, MLP_W, 0, stream>>>(z, fin_W, fin_b, freq,
                                                 mid_W, mid_b, fout_W, hT);
    cast_bf16_kernel<<<(ROWS*D_MODEL)/(256*8), 256, 0, stream>>>(u, Abf, ROWS*D_MODEL);
    transpose_cast_kernel<<<dim3(D3/64, D_MODEL/64), 256, 0, stream>>>(
        proj_W, BpT1, D_MODEL, D3);
    gemm_mfma_kernel<<<dim3(D3/128, ROWS/128), 256, 0, stream>>>(
        Abf, BpT1, proj_b, up, ROWS, D3, D_MODEL);
    convprep_kernel<<<dim3(D_MODEL/64, MAX_LEN/64, NBATCH), 256, 0, stream>>>(
        up, conv_W, conv_b, seqT, gate);
    transpose_cast_kernel<<<dim3(D_MODEL/64, D_MODEL/64), 256, 0, stream>>>(
        out_W, BpT2, D_MODEL, D_MODEL);
    longconv_kernel<<<NBATCH*D_MODEL, 256, 0, stream>>>(seqT, hT, fbias);
    gatemul_kernel<<<dim3(D_MODEL/64, MAX_LEN/64, NBATCH), 256, 0, stream>>>(
        seqT, gate, Afinbf);
    gemm_mfma_kernel<<<dim3(D_MODEL/128, ROWS/128), 256, 0, stream>>>(
        Afinbf, BpT2, out_b, out, ROWS, D_MODEL, D_MODEL);
}

// Round 3
// 639.390 us; speedup vs baseline: 3.1183x; 1.8946x over previous
//
#include <hip/hip_runtime.h>
#include <math.h>

#define MAX_LEN 4096
#define D_MODEL 768
#define PE_DIM 65
#define MLP_W 64
#define NBATCH 4
#define D3 2304               // (ORDER+1)*D_MODEL
#define ROWS (NBATCH*MAX_LEN) // 16384

typedef unsigned short u16;
typedef unsigned int u32;
typedef float f4 __attribute__((ext_vector_type(4)));
typedef __bf16 bf16x8 __attribute__((ext_vector_type(8)));
typedef float f32x4 __attribute__((ext_vector_type(4)));

__device__ inline u16 f2bf(float x) {
    u32 u = __float_as_uint(x);
    u += 0x7fffu + ((u >> 16) & 1u);   // round-to-nearest-even
    return (u16)(u >> 16);
}
__device__ inline float bf2f(u16 v) { return __uint_as_float((u32)v << 16); }
__device__ inline u32 pk2(float a, float b) {
    return (u32)f2bf(a) | ((u32)f2bf(b) << 16);
}

// ---------------------------------------------------------------------------
// K1: filter MLP + decay -> hT (D_MODEL x MAX_LEN, d-major)
// ---------------------------------------------------------------------------
__global__ void filter_kernel(const float* __restrict__ z,
                              const float* __restrict__ fin_W,
                              const float* __restrict__ fin_b,
                              const float* __restrict__ freq,
                              const float* __restrict__ mid_W,
                              const float* __restrict__ mid_b,
                              const float* __restrict__ fout_W,
                              float* __restrict__ hT)
{
    int t = blockIdx.x;
    int j = threadIdx.x;  // 0..63
    __shared__ float zrow[PE_DIM];
    __shared__ float k1[MLP_W];
    __shared__ float k2[MLP_W];
    __shared__ float k3[MLP_W];
    for (int i = j; i < PE_DIM; i += MLP_W) zrow[i] = z[t*PE_DIM + i];
    __syncthreads();
    float fj = freq[j];
    float acc = fin_b[j];
    for (int i = 0; i < PE_DIM; ++i) acc += zrow[i]*fin_W[i*MLP_W + j];
    k1[j] = sinf(fj*acc);
    __syncthreads();
    acc = mid_b[j];
    for (int i = 0; i < MLP_W; ++i) acc += k1[i]*mid_W[i*MLP_W + j];
    k2[j] = sinf(fj*acc);
    __syncthreads();
    acc = mid_b[MLP_W + j];
    for (int i = 0; i < MLP_W; ++i) acc += k2[i]*mid_W[MLP_W*MLP_W + i*MLP_W + j];
    k3[j] = sinf(fj*acc);
    __syncthreads();
    const float MIND = -3.0701134573253944f;   // ln(0.01)/1.5
    const float MAXD = -15.350567286626972f;   // ln(0.01)/0.3
    float tt = (float)t * (1.0f/(float)(MAX_LEN-1));
    for (int m = 0; m < D_MODEL/MLP_W; ++m) {
        int d = j + MLP_W*m;
        float a = 0.f;
        for (int i = 0; i < MLP_W; ++i) a += k3[i]*fout_W[i*D_MODEL + d];
        float delta = MIND + (MAXD-MIND)*((float)d*(1.0f/(float)(D_MODEL-1)));
        float dec = expf(-tt*fabsf(delta));
        hT[(size_t)d*MAX_LEN + t] = a*dec;
    }
}

// ---------------------------------------------------------------------------
// cast fp32 -> bf16 (elementwise, 8/thread)
// ---------------------------------------------------------------------------
__global__ void cast_bf16_kernel(const float* __restrict__ src,
                                 u16* __restrict__ dst, int n)
{
    int i = (blockIdx.x*256 + threadIdx.x)*8;
    if (i + 7 >= n) {
        for (int j = i; j < n; ++j) dst[j] = f2bf(src[j]);
        return;
    }
    float4 a = *(const float4*)(src + i);
    float4 b = *(const float4*)(src + i + 4);
    uint4 o;
    o.x = pk2(a.x, a.y);
    o.y = pk2(a.z, a.w);
    o.z = pk2(b.x, b.y);
    o.w = pk2(b.z, b.w);
    *(uint4*)(dst + i) = o;
}

// ---------------------------------------------------------------------------
// transpose + cast: src (R x C fp32) -> dst (C x R bf16)
// ---------------------------------------------------------------------------
__global__ void transpose_cast_kernel(const float* __restrict__ src,
                                      u16* __restrict__ dst, int R, int C)
{
    __shared__ u16 tile[64][65];
    int c0 = blockIdx.x*64, r0 = blockIdx.y*64;
    int tid = threadIdx.x;
    #pragma unroll
    for (int p = 0; p < 16; ++p) {
        int idx = tid + 256*p;
        int rr = idx >> 6, cc = idx & 63;
        tile[rr][cc] = f2bf(src[(size_t)(r0+rr)*C + c0 + cc]);
    }
    __syncthreads();
    #pragma unroll
    for (int p = 0; p < 16; ++p) {
        int idx = tid + 256*p;
        int cr = idx >> 6, rc = idx & 63;
        dst[(size_t)(c0+cr)*R + r0 + rc] = tile[rc][cr];
    }
}

// ---------------------------------------------------------------------------
// K2/K6: C[M,N] = A[M,K]bf16 @ Bt[N,K]bf16 + bias  (MFMA 16x16x32, 128x128 tile)
// ---------------------------------------------------------------------------
__launch_bounds__(256)
__global__ void gemm_mfma_kernel(const u16* __restrict__ A,   // M x K
                                 const u16* __restrict__ Bt,  // N x K
                                 const float* __restrict__ bias,
                                 float* __restrict__ C,
                                 int M, int N, int K)
{
    __shared__ __align__(16) u16 As[128*40];
    __shared__ __align__(16) u16 Bs[128*40];
    int tid = threadIdx.x;
    int lane = tid & 63, w = tid >> 6;
    int wm = (w >> 1)*64, wn = (w & 1)*64;
    int lrow = lane & 15, lch = lane >> 4;
    int m0 = blockIdx.y * 128, n0 = blockIdx.x * 128;

    int srow = tid >> 1, sc = (tid & 1)*16;
    const u16* Ag = A + (size_t)(m0 + srow)*K + sc;
    const u16* Bg = Bt + (size_t)(n0 + srow)*K + sc;
    int soff = srow*40 + sc;

    f32x4 acc[4][4];
    #pragma unroll
    for (int i = 0; i < 4; ++i)
        #pragma unroll
        for (int j = 0; j < 4; ++j)
            acc[i][j] = (f32x4){0.f,0.f,0.f,0.f};

    for (int k0 = 0; k0 < K; k0 += 32) {
        float4 a0 = *(const float4*)(Ag + k0);
        float4 a1 = *(const float4*)(Ag + k0 + 8);
        float4 b0 = *(const float4*)(Bg + k0);
        float4 b1 = *(const float4*)(Bg + k0 + 8);
        __syncthreads();
        *(float4*)&As[soff]   = a0;
        *(float4*)&As[soff+8] = a1;
        *(float4*)&Bs[soff]   = b0;
        *(float4*)&Bs[soff+8] = b1;
        __syncthreads();
        bf16x8 af[4], bfr[4];
        #pragma unroll
        for (int i = 0; i < 4; ++i) {
            af[i]  = *(const bf16x8*)&As[(wm + i*16 + lrow)*40 + lch*8];
            bfr[i] = *(const bf16x8*)&Bs[(wn + i*16 + lrow)*40 + lch*8];
        }
        #pragma unroll
        for (int mt = 0; mt < 4; ++mt)
            #pragma unroll
            for (int nt = 0; nt < 4; ++nt)
                acc[mt][nt] = __builtin_amdgcn_mfma_f32_16x16x32_bf16(
                    af[mt], bfr[nt], acc[mt][nt], 0, 0, 0);
    }
    #pragma unroll
    for (int nt = 0; nt < 4; ++nt) {
        int n = n0 + wn + nt*16 + lrow;
        float bv = bias[n];
        #pragma unroll
        for (int mt = 0; mt < 4; ++mt) {
            int m = m0 + wm + mt*16 + lch*4;
            #pragma unroll
            for (int r = 0; r < 4; ++r)
                C[(size_t)(m + r)*N + n] = acc[mt][nt][r] + bv;
        }
    }
}

// ---------------------------------------------------------------------------
// K3: short conv (width 3, causal) + split + seq=x0*v, gate=x1
// ---------------------------------------------------------------------------
__global__ void convprep_kernel(const float* __restrict__ up,
                                const float* __restrict__ conv_W,
                                const float* __restrict__ conv_b,
                                float* __restrict__ seqT,
                                float* __restrict__ gate)
{
    __shared__ float sb[64][65];
    int d0 = blockIdx.x * 64;
    int t0 = blockIdx.y * 64;
    int b  = blockIdx.z;
    int tid = threadIdx.x;
    #pragma unroll
    for (int i = 0; i < 16; ++i) {
        int idx = tid + 256*i;
        int trow = idx >> 6, dcol = idx & 63;
        int t = t0 + trow;
        int d = d0 + dcol;
        size_t r = ((size_t)b*MAX_LEN + t)*D3;
        float uc[3];
        #pragma unroll
        for (int g = 0; g < 3; ++g) {
            int c = d + g*D_MODEL;
            float u0 = up[r + c];
            float u1 = (t >= 1) ? up[r - D3 + c]   : 0.f;
            float u2 = (t >= 2) ? up[r - 2*D3 + c] : 0.f;
            uc[g] = conv_W[c]*u2 + conv_W[D3 + c]*u1 + conv_W[2*D3 + c]*u0 + conv_b[c];
        }
        sb[trow][dcol] = uc[0]*uc[2];
        gate[((size_t)b*MAX_LEN + t)*D_MODEL + d] = uc[1];
    }
    __syncthreads();
    #pragma unroll
    for (int i = 0; i < 16; ++i) {
        int idx = tid + 256*i;
        int drow = idx >> 6, tcol = idx & 63;
        seqT[((size_t)b*D_MODEL + d0 + drow)*MAX_LEN + t0 + tcol] = sb[tcol][drow];
    }
}

// ---------------------------------------------------------------------------
// K4: long causal depthwise conv via block-Toeplitz MFMA, one block per (b,d).
//   y[t] = sum_{s<=t} seq[s]*h[t-s] + seq[t]*filt_bias[d]
// Tiles of 16: block(ti,sj) of the Toeplitz matrix depends only on ti-sj.
// For slab j (D0 = 32j+16): A[i][k] = h[D0+i-k] (16x32, zero-pad h<0),
// B[k][n] = seq[16*tn - D0 + k] for 16 output tiles tn -> mfma_16x16x32_bf16.
// 16 tn-groups interleaved across 4 waves; group g needs slabs j<=8g+7 ->
// rounds r=0..15 of 8 slabs, group active iff g>=r (skew-balanced).
// seq LDS swizzled at 16B-quad granularity (P=Q+(Q>>3)) -> B-reads <=2-way.
// ---------------------------------------------------------------------------
__launch_bounds__(256)
__global__ void longconv_mfma_kernel(float* seq_io,                 // (B,768,L) in/out
                                     const float* __restrict__ hT,  // (768,L)
                                     const float* __restrict__ filt_bias)
{
    __shared__ __align__(16) u16 sq[4896];    // swizzled bf16 seq, 256-elem zero pad below
    __shared__ __align__(16) u16 hp[4112];    // bf16 h, 16-elem zero pad below
    __shared__ __align__(16) u16 A_s[8*640];  // 8 slabs, 16 rows x 40 u16 (32 + pad)

    int bd  = blockIdx.x;
    int d   = bd % D_MODEL;
    int tid = threadIdx.x;
    int lane = tid & 63, w = tid >> 6;
    int lrow = lane & 15, lch = lane >> 4;    // n (or i) , quad

    float* src = seq_io + (size_t)bd*MAX_LEN;

    // --- stage seq -> sq (bf16, swizzled), h -> hp (bf16, linear) ---
    for (int q = tid; q < 544; q += 256) {          // logical 16B-quads, 32 pad + 512 data
        int p = ((q + (q >> 3)) << 3);              // physical u16 index
        uint4 o = make_uint4(0u, 0u, 0u, 0u);
        if (q >= 32) {
            const float4 f0 = *(const float4*)&src[(q-32)*8];
            const float4 f1 = *(const float4*)&src[(q-32)*8 + 4];
            o.x = pk2(f0.x, f0.y); o.y = pk2(f0.z, f0.w);
            o.z = pk2(f1.x, f1.y); o.w = pk2(f1.z, f1.w);
        }
        *(uint4*)&sq[p] = o;
    }
    const float* hsrc = hT + (size_t)d*MAX_LEN;
    for (int q = tid; q < 514; q += 256) {          // 2 pad quads + 512 data
        uint4 o = make_uint4(0u, 0u, 0u, 0u);
        if (q >= 2) {
            const float4 f0 = *(const float4*)&hsrc[(q-2)*8];
            const float4 f1 = *(const float4*)&hsrc[(q-2)*8 + 4];
            o.x = pk2(f0.x, f0.y); o.y = pk2(f0.z, f0.w);
            o.z = pk2(f1.x, f1.y); o.w = pk2(f1.z, f1.w);
        }
        *(uint4*)&hp[q*8] = o;
    }

    f32x4 acc[4];
    #pragma unroll
    for (int g4 = 0; g4 < 4; ++g4) acc[g4] = (f32x4){0.f,0.f,0.f,0.f};

    // A-build assignment: tid = slab(3) | half(1) | i(4)
    int slab_b = tid >> 5;
    int half_b = (tid >> 4) & 1;
    int i_b    = tid & 15;
    u32* bld = (u32*)&A_s[slab_b*640 + i_b*40 + half_b*16];

    for (int r = 0; r < 16; ++r) {
        __syncthreads();   // prior round's MFMA reads done (and staging on r=0)
        // build 8 Toeplitz slabs: A[i][k] = hp[32 + 256r + 32*slab + i - k]
        {
            int hbase = 32 + 256*r + 32*slab_b + i_b - half_b*16;
            #pragma unroll
            for (int kk2 = 0; kk2 < 8; ++kk2) {
                u16 v0 = hp[hbase - 2*kk2];
                u16 v1 = hp[hbase - 2*kk2 - 1];
                bld[kk2] = (u32)v0 | ((u32)v1 << 16);
            }
        }
        __syncthreads();
        // A-frags (shared across this wave's 4 groups)
        bf16x8 afr[8];
        #pragma unroll
        for (int s = 0; s < 8; ++s)
            afr[s] = *(const bf16x8*)&A_s[s*640 + lrow*40 + lch*8];
        #pragma unroll
        for (int g4 = 0; g4 < 4; ++g4) {
            int g = w + 4*g4;
            if (g < r) continue;                    // wave-uniform skip
            int ebase = 256 + 256*(g - r) - 16 + 16*lrow + 8*lch;
            #pragma unroll
            for (int s = 0; s < 8; ++s) {
                int elem = ebase - 32*s;            // multiple of 8
                int Q = elem >> 3;
                const bf16x8 bfr = *(const bf16x8*)&sq[(Q + (Q >> 3)) << 3];
                acc[g4] = __builtin_amdgcn_mfma_f32_16x16x32_bf16(
                    afr[s], bfr, acc[g4], 0, 0, 0);
            }
        }
    }
    __syncthreads();

    // epilogue: y = acc + filt_bias[d]*seq ; write fp32 in-place
    float fb = filt_bias[d];
    #pragma unroll
    for (int g4 = 0; g4 < 4; ++g4) {
        int g = w + 4*g4;
        int t0 = 256*g + 16*lrow + 4*lch;
        f4 o;
        #pragma unroll
        for (int r4 = 0; r4 < 4; ++r4) {
            int elem = 256 + t0 + r4;
            int Q = elem >> 3;
            float sv = bf2f(sq[(((Q + (Q >> 3)) << 3)) | (elem & 7)]);
            o[r4] = acc[g4][r4] + fb*sv;
        }
        *(f4*)&src[t0] = o;
    }
}

// ---------------------------------------------------------------------------
// K5: Afin(bf16)[b*L+t, d] = yT[b,d,t] * gate[b*L+t, d]
// ---------------------------------------------------------------------------
__global__ void gatemul_kernel(const float* __restrict__ yT,
                               const float* __restrict__ gate,
                               u16* __restrict__ Afin)
{
    __shared__ float tb[64][65];
    int d0 = blockIdx.x * 64;
    int t0 = blockIdx.y * 64;
    int b  = blockIdx.z;
    int tid = threadIdx.x;
    #pragma unroll
    for (int i = 0; i < 16; ++i) {
        int idx = tid + 256*i;
        int drow = idx >> 6, tcol = idx & 63;
        tb[drow][tcol] = yT[((size_t)b*D_MODEL + d0 + drow)*MAX_LEN + t0 + tcol];
    }
    __syncthreads();
    #pragma unroll
    for (int i = 0; i < 16; ++i) {
        int idx = tid + 256*i;
        int trow = idx >> 6, dcol = idx & 63;
        size_t r = ((size_t)b*MAX_LEN + t0 + trow)*D_MODEL + d0 + dcol;
        Afin[r] = f2bf(tb[dcol][trow] * gate[r]);
    }
}

// ---------------------------------------------------------------------------
extern "C" void kernel_launch(void* const* d_in, const int* in_sizes, int n_in,
                              void* d_out, int out_size, void* d_ws, size_t ws_size,
                              hipStream_t stream)
{
    (void)in_sizes; (void)n_in; (void)out_size; (void)ws_size;
    const float* u      = (const float*)d_in[0];
    const float* z      = (const float*)d_in[1];
    const float* fin_W  = (const float*)d_in[2];
    const float* fin_b  = (const float*)d_in[3];
    const float* freq   = (const float*)d_in[4];
    const float* mid_W  = (const float*)d_in[5];
    const float* mid_b  = (const float*)d_in[6];
    const float* fout_W = (const float*)d_in[7];
    const float* proj_W = (const float*)d_in[8];
    const float* proj_b = (const float*)d_in[9];
    const float* conv_W = (const float*)d_in[10];
    const float* conv_b = (const float*)d_in[11];
    const float* fbias  = (const float*)d_in[12];
    const float* out_W  = (const float*)d_in[13];
    const float* out_b  = (const float*)d_in[14];
    float* out = (float*)d_out;

    // ws layout (floats): hT | up | seqR | gateR   (total 66.05M f = 264 MB)
    float* ws    = (float*)d_ws;
    float* hT    = ws;                                   //  3,145,728 f
    float* up    = hT   + (size_t)D_MODEL*MAX_LEN;       // 37,748,736 f
    float* seqR  = up   + (size_t)ROWS*D3;               // 12,582,912 f
    float* gateR = seqR + (size_t)NBATCH*D_MODEL*MAX_LEN;// 12,582,912 f
    // bf16 aliases in regions dead at time of use:
    u16* Abf    = (u16*)seqR;                 // u bf16 (dead after GEMM1)
    u16* BpT1   = (u16*)gateR;                // proj_W^T bf16 (dead after GEMM1)
    u16* Afinbf = (u16*)up;                   // up fp32 dead after convprep
    u16* BpT2   = (u16*)(up + (size_t)20*1024*1024);  // out_W^T bf16, dead up region
    float* seqT = seqR;
    float* gate = gateR;

    filter_kernel<<<MAX_LEN, MLP_W, 0, stream>>>(z, fin_W, fin_b, freq,
                                                 mid_W, mid_b, fout_W, hT);
    cast_bf16_kernel<<<(ROWS*D_MODEL)/(256*8), 256, 0, stream>>>(u, Abf, ROWS*D_MODEL);
    transpose_cast_kernel<<<dim3(D3/64, D_MODEL/64), 256, 0, stream>>>(
        proj_W, BpT1, D_MODEL, D3);
    gemm_mfma_kernel<<<dim3(D3/128, ROWS/128), 256, 0, stream>>>(
        Abf, BpT1, proj_b, up, ROWS, D3, D_MODEL);
    convprep_kernel<<<dim3(D_MODEL/64, MAX_LEN/64, NBATCH), 256, 0, stream>>>(
        up, conv_W, conv_b, seqT, gate);
    transpose_cast_kernel<<<dim3(D_MODEL/64, D_MODEL/64), 256, 0, stream>>>(
        out_W, BpT2, D_MODEL, D_MODEL);
    longconv_mfma_kernel<<<NBATCH*D_MODEL, 256, 0, stream>>>(seqT, hT, fbias);
    gatemul_kernel<<<dim3(D_MODEL/64, MAX_LEN/64, NBATCH), 256, 0, stream>>>(
        seqT, gate, Afinbf);
    gemm_mfma_kernel<<<dim3(D_MODEL/128, ROWS/128), 256, 0, stream>>>(
        Afinbf, BpT2, out_b, out, ROWS, D_MODEL, D_MODEL);
}

// Round 4
// 619.951 us; speedup vs baseline: 3.2160x; 1.0314x over previous
//
#include <hip/hip_runtime.h>
#include <math.h>

#define MAX_LEN 4096
#define D_MODEL 768
#define PE_DIM 65
#define MLP_W 64
#define NBATCH 4
#define D3 2304               // (ORDER+1)*D_MODEL
#define ROWS (NBATCH*MAX_LEN) // 16384

typedef unsigned short u16;
typedef unsigned int u32;
typedef float f4 __attribute__((ext_vector_type(4)));
typedef __bf16 bf16x8 __attribute__((ext_vector_type(8)));
typedef float f32x4 __attribute__((ext_vector_type(4)));

__device__ inline u16 f2bf(float x) {
    u32 u = __float_as_uint(x);
    u += 0x7fffu + ((u >> 16) & 1u);   // round-to-nearest-even
    return (u16)(u >> 16);
}
__device__ inline float bf2f(u16 v) { return __uint_as_float((u32)v << 16); }
__device__ inline u32 pk2(float a, float b) {
    return (u32)f2bf(a) | ((u32)f2bf(b) << 16);
}

// ---------------------------------------------------------------------------
// K1: filter MLP + decay -> hTt (MAX_LEN x D_MODEL, t-major, coalesced writes)
// ---------------------------------------------------------------------------
__global__ void filter_kernel(const float* __restrict__ z,
                              const float* __restrict__ fin_W,
                              const float* __restrict__ fin_b,
                              const float* __restrict__ freq,
                              const float* __restrict__ mid_W,
                              const float* __restrict__ mid_b,
                              const float* __restrict__ fout_W,
                              float* __restrict__ hTt)
{
    int t = blockIdx.x;
    int j = threadIdx.x;  // 0..63
    __shared__ float zrow[PE_DIM];
    __shared__ float k1[MLP_W];
    __shared__ float k2[MLP_W];
    __shared__ float k3[MLP_W];
    for (int i = j; i < PE_DIM; i += MLP_W) zrow[i] = z[t*PE_DIM + i];
    __syncthreads();
    float fj = freq[j];
    float acc = fin_b[j];
    for (int i = 0; i < PE_DIM; ++i) acc += zrow[i]*fin_W[i*MLP_W + j];
    k1[j] = sinf(fj*acc);
    __syncthreads();
    acc = mid_b[j];
    for (int i = 0; i < MLP_W; ++i) acc += k1[i]*mid_W[i*MLP_W + j];
    k2[j] = sinf(fj*acc);
    __syncthreads();
    acc = mid_b[MLP_W + j];
    for (int i = 0; i < MLP_W; ++i) acc += k2[i]*mid_W[MLP_W*MLP_W + i*MLP_W + j];
    k3[j] = sinf(fj*acc);
    __syncthreads();
    const float MIND = -3.0701134573253944f;   // ln(0.01)/1.5
    const float MAXD = -15.350567286626972f;   // ln(0.01)/0.3
    float tt = (float)t * (1.0f/(float)(MAX_LEN-1));
    for (int m = 0; m < D_MODEL/MLP_W; ++m) {
        int d = j + MLP_W*m;
        float a = 0.f;
        for (int i = 0; i < MLP_W; ++i) a += k3[i]*fout_W[i*D_MODEL + d];
        float delta = MIND + (MAXD-MIND)*((float)d*(1.0f/(float)(D_MODEL-1)));
        float dec = expf(-tt*fabsf(delta));
        hTt[(size_t)t*D_MODEL + d] = a*dec;   // coalesced: lanes -> consecutive d
    }
}

// ---------------------------------------------------------------------------
// fp32 transpose: src (R x C) -> dst (C x R), 64x64 LDS tiles
// ---------------------------------------------------------------------------
__global__ void transpose_f32_kernel(const float* __restrict__ src,
                                     float* __restrict__ dst, int R, int C)
{
    __shared__ float tile[64][65];
    int c0 = blockIdx.x*64, r0 = blockIdx.y*64;
    int tid = threadIdx.x;
    #pragma unroll
    for (int p = 0; p < 16; ++p) {
        int idx = tid + 256*p;
        int rr = idx >> 6, cc = idx & 63;
        tile[rr][cc] = src[(size_t)(r0+rr)*C + c0 + cc];
    }
    __syncthreads();
    #pragma unroll
    for (int p = 0; p < 16; ++p) {
        int idx = tid + 256*p;
        int cr = idx >> 6, rc = idx & 63;
        dst[(size_t)(c0+cr)*R + r0 + rc] = tile[rc][cr];
    }
}

// ---------------------------------------------------------------------------
// cast fp32 -> bf16 (elementwise, 8/thread)
// ---------------------------------------------------------------------------
__global__ void cast_bf16_kernel(const float* __restrict__ src,
                                 u16* __restrict__ dst, int n)
{
    int i = (blockIdx.x*256 + threadIdx.x)*8;
    if (i + 7 >= n) {
        for (int j = i; j < n; ++j) dst[j] = f2bf(src[j]);
        return;
    }
    float4 a = *(const float4*)(src + i);
    float4 b = *(const float4*)(src + i + 4);
    uint4 o;
    o.x = pk2(a.x, a.y);
    o.y = pk2(a.z, a.w);
    o.z = pk2(b.x, b.y);
    o.w = pk2(b.z, b.w);
    *(uint4*)(dst + i) = o;
}

// ---------------------------------------------------------------------------
// transpose + cast: src (R x C fp32) -> dst (C x R bf16)
// ---------------------------------------------------------------------------
__global__ void transpose_cast_kernel(const float* __restrict__ src,
                                      u16* __restrict__ dst, int R, int C)
{
    __shared__ u16 tile[64][65];
    int c0 = blockIdx.x*64, r0 = blockIdx.y*64;
    int tid = threadIdx.x;
    #pragma unroll
    for (int p = 0; p < 16; ++p) {
        int idx = tid + 256*p;
        int rr = idx >> 6, cc = idx & 63;
        tile[rr][cc] = f2bf(src[(size_t)(r0+rr)*C + c0 + cc]);
    }
    __syncthreads();
    #pragma unroll
    for (int p = 0; p < 16; ++p) {
        int idx = tid + 256*p;
        int cr = idx >> 6, rc = idx & 63;
        dst[(size_t)(c0+cr)*R + r0 + rc] = tile[rc][cr];
    }
}

// ---------------------------------------------------------------------------
// K2/K6: C[M,N] = A[M,K]bf16 @ Bt[N,K]bf16 + bias  (MFMA 16x16x32, 128x128 tile)
// ---------------------------------------------------------------------------
__launch_bounds__(256)
__global__ void gemm_mfma_kernel(const u16* __restrict__ A,   // M x K
                                 const u16* __restrict__ Bt,  // N x K
                                 const float* __restrict__ bias,
                                 float* __restrict__ C,
                                 int M, int N, int K)
{
    __shared__ __align__(16) u16 As[128*40];
    __shared__ __align__(16) u16 Bs[128*40];
    int tid = threadIdx.x;
    int lane = tid & 63, w = tid >> 6;
    int wm = (w >> 1)*64, wn = (w & 1)*64;
    int lrow = lane & 15, lch = lane >> 4;
    int m0 = blockIdx.y * 128, n0 = blockIdx.x * 128;

    int srow = tid >> 1, sc = (tid & 1)*16;
    const u16* Ag = A + (size_t)(m0 + srow)*K + sc;
    const u16* Bg = Bt + (size_t)(n0 + srow)*K + sc;
    int soff = srow*40 + sc;

    f32x4 acc[4][4];
    #pragma unroll
    for (int i = 0; i < 4; ++i)
        #pragma unroll
        for (int j = 0; j < 4; ++j)
            acc[i][j] = (f32x4){0.f,0.f,0.f,0.f};

    for (int k0 = 0; k0 < K; k0 += 32) {
        float4 a0 = *(const float4*)(Ag + k0);
        float4 a1 = *(const float4*)(Ag + k0 + 8);
        float4 b0 = *(const float4*)(Bg + k0);
        float4 b1 = *(const float4*)(Bg + k0 + 8);
        __syncthreads();
        *(float4*)&As[soff]   = a0;
        *(float4*)&As[soff+8] = a1;
        *(float4*)&Bs[soff]   = b0;
        *(float4*)&Bs[soff+8] = b1;
        __syncthreads();
        bf16x8 af[4], bfr[4];
        #pragma unroll
        for (int i = 0; i < 4; ++i) {
            af[i]  = *(const bf16x8*)&As[(wm + i*16 + lrow)*40 + lch*8];
            bfr[i] = *(const bf16x8*)&Bs[(wn + i*16 + lrow)*40 + lch*8];
        }
        #pragma unroll
        for (int mt = 0; mt < 4; ++mt)
            #pragma unroll
            for (int nt = 0; nt < 4; ++nt)
                acc[mt][nt] = __builtin_amdgcn_mfma_f32_16x16x32_bf16(
                    af[mt], bfr[nt], acc[mt][nt], 0, 0, 0);
    }
    #pragma unroll
    for (int nt = 0; nt < 4; ++nt) {
        int n = n0 + wn + nt*16 + lrow;
        float bv = bias[n];
        #pragma unroll
        for (int mt = 0; mt < 4; ++mt) {
            int m = m0 + wm + mt*16 + lch*4;
            #pragma unroll
            for (int r = 0; r < 4; ++r)
                C[(size_t)(m + r)*N + n] = acc[mt][nt][r] + bv;
        }
    }
}

// ---------------------------------------------------------------------------
// K3: short conv (width 3, causal) + split + seq=x0*v, gate=x1
// ---------------------------------------------------------------------------
__global__ void convprep_kernel(const float* __restrict__ up,
                                const float* __restrict__ conv_W,
                                const float* __restrict__ conv_b,
                                float* __restrict__ seqT,
                                float* __restrict__ gate)
{
    __shared__ float sb[64][65];
    int d0 = blockIdx.x * 64;
    int t0 = blockIdx.y * 64;
    int b  = blockIdx.z;
    int tid = threadIdx.x;
    #pragma unroll
    for (int i = 0; i < 16; ++i) {
        int idx = tid + 256*i;
        int trow = idx >> 6, dcol = idx & 63;
        int t = t0 + trow;
        int d = d0 + dcol;
        size_t r = ((size_t)b*MAX_LEN + t)*D3;
        float uc[3];
        #pragma unroll
        for (int g = 0; g < 3; ++g) {
            int c = d + g*D_MODEL;
            float u0 = up[r + c];
            float u1 = (t >= 1) ? up[r - D3 + c]   : 0.f;
            float u2 = (t >= 2) ? up[r - 2*D3 + c] : 0.f;
            uc[g] = conv_W[c]*u2 + conv_W[D3 + c]*u1 + conv_W[2*D3 + c]*u0 + conv_b[c];
        }
        sb[trow][dcol] = uc[0]*uc[2];
        gate[((size_t)b*MAX_LEN + t)*D_MODEL + d] = uc[1];
    }
    __syncthreads();
    #pragma unroll
    for (int i = 0; i < 16; ++i) {
        int idx = tid + 256*i;
        int drow = idx >> 6, tcol = idx & 63;
        seqT[((size_t)b*D_MODEL + d0 + drow)*MAX_LEN + t0 + tcol] = sb[tcol][drow];
    }
}

// ---------------------------------------------------------------------------
// K4: long causal depthwise conv via block-Toeplitz MFMA, one block per (b,d).
// ---------------------------------------------------------------------------
__launch_bounds__(256)
__global__ void longconv_mfma_kernel(float* seq_io,                 // (B,768,L) in/out
                                     const float* __restrict__ hT,  // (768,L)
                                     const float* __restrict__ filt_bias)
{
    __shared__ __align__(16) u16 sq[4896];    // swizzled bf16 seq, 256-elem zero pad below
    __shared__ __align__(16) u16 hp[4112];    // bf16 h, 16-elem zero pad below
    __shared__ __align__(16) u16 A_s[8*640];  // 8 slabs, 16 rows x 40 u16 (32 + pad)

    int bd  = blockIdx.x;
    int d   = bd % D_MODEL;
    int tid = threadIdx.x;
    int lane = tid & 63, w = tid >> 6;
    int lrow = lane & 15, lch = lane >> 4;    // n (or i) , quad

    float* src = seq_io + (size_t)bd*MAX_LEN;

    // --- stage seq -> sq (bf16, swizzled), h -> hp (bf16, linear) ---
    for (int q = tid; q < 544; q += 256) {          // logical 16B-quads, 32 pad + 512 data
        int p = ((q + (q >> 3)) << 3);              // physical u16 index
        uint4 o = make_uint4(0u, 0u, 0u, 0u);
        if (q >= 32) {
            const float4 f0 = *(const float4*)&src[(q-32)*8];
            const float4 f1 = *(const float4*)&src[(q-32)*8 + 4];
            o.x = pk2(f0.x, f0.y); o.y = pk2(f0.z, f0.w);
            o.z = pk2(f1.x, f1.y); o.w = pk2(f1.z, f1.w);
        }
        *(uint4*)&sq[p] = o;
    }
    const float* hsrc = hT + (size_t)d*MAX_LEN;
    for (int q = tid; q < 514; q += 256) {          // 2 pad quads + 512 data
        uint4 o = make_uint4(0u, 0u, 0u, 0u);
        if (q >= 2) {
            const float4 f0 = *(const float4*)&hsrc[(q-2)*8];
            const float4 f1 = *(const float4*)&hsrc[(q-2)*8 + 4];
            o.x = pk2(f0.x, f0.y); o.y = pk2(f0.z, f0.w);
            o.z = pk2(f1.x, f1.y); o.w = pk2(f1.z, f1.w);
        }
        *(uint4*)&hp[q*8] = o;
    }

    f32x4 acc[4];
    #pragma unroll
    for (int g4 = 0; g4 < 4; ++g4) acc[g4] = (f32x4){0.f,0.f,0.f,0.f};

    // A-build assignment: tid = slab(3) | half(1) | i(4)
    int slab_b = tid >> 5;
    int half_b = (tid >> 4) & 1;
    int i_b    = tid & 15;
    u32* bld = (u32*)&A_s[slab_b*640 + i_b*40 + half_b*16];

    for (int r = 0; r < 16; ++r) {
        __syncthreads();   // prior round's MFMA reads done (and staging on r=0)
        // build 8 Toeplitz slabs: A[i][k] = hp[32 + 256r + 32*slab + i - k]
        {
            int hbase = 32 + 256*r + 32*slab_b + i_b - half_b*16;
            #pragma unroll
            for (int kk2 = 0; kk2 < 8; ++kk2) {
                u16 v0 = hp[hbase - 2*kk2];
                u16 v1 = hp[hbase - 2*kk2 - 1];
                bld[kk2] = (u32)v0 | ((u32)v1 << 16);
            }
        }
        __syncthreads();
        // A-frags (shared across this wave's 4 groups)
        bf16x8 afr[8];
        #pragma unroll
        for (int s = 0; s < 8; ++s)
            afr[s] = *(const bf16x8*)&A_s[s*640 + lrow*40 + lch*8];
        #pragma unroll
        for (int g4 = 0; g4 < 4; ++g4) {
            int g = w + 4*g4;
            if (g < r) continue;                    // wave-uniform skip
            int ebase = 256 + 256*(g - r) - 16 + 16*lrow + 8*lch;
            #pragma unroll
            for (int s = 0; s < 8; ++s) {
                int elem = ebase - 32*s;            // multiple of 8
                int Q = elem >> 3;
                const bf16x8 bfr = *(const bf16x8*)&sq[(Q + (Q >> 3)) << 3];
                acc[g4] = __builtin_amdgcn_mfma_f32_16x16x32_bf16(
                    afr[s], bfr, acc[g4], 0, 0, 0);
            }
        }
    }
    __syncthreads();

    // epilogue: y = acc + filt_bias[d]*seq ; write fp32 in-place
    float fb = filt_bias[d];
    #pragma unroll
    for (int g4 = 0; g4 < 4; ++g4) {
        int g = w + 4*g4;
        int t0 = 256*g + 16*lrow + 4*lch;
        f4 o;
        #pragma unroll
        for (int r4 = 0; r4 < 4; ++r4) {
            int elem = 256 + t0 + r4;
            int Q = elem >> 3;
            float sv = bf2f(sq[(((Q + (Q >> 3)) << 3)) | (elem & 7)]);
            o[r4] = acc[g4][r4] + fb*sv;
        }
        *(f4*)&src[t0] = o;
    }
}

// ---------------------------------------------------------------------------
// K5: Afin(bf16)[b*L+t, d] = yT[b,d,t] * gate[b*L+t, d]
// ---------------------------------------------------------------------------
__global__ void gatemul_kernel(const float* __restrict__ yT,
                               const float* __restrict__ gate,
                               u16* __restrict__ Afin)
{
    __shared__ float tb[64][65];
    int d0 = blockIdx.x * 64;
    int t0 = blockIdx.y * 64;
    int b  = blockIdx.z;
    int tid = threadIdx.x;
    #pragma unroll
    for (int i = 0; i < 16; ++i) {
        int idx = tid + 256*i;
        int drow = idx >> 6, tcol = idx & 63;
        tb[drow][tcol] = yT[((size_t)b*D_MODEL + d0 + drow)*MAX_LEN + t0 + tcol];
    }
    __syncthreads();
    #pragma unroll
    for (int i = 0; i < 16; ++i) {
        int idx = tid + 256*i;
        int trow = idx >> 6, dcol = idx & 63;
        size_t r = ((size_t)b*MAX_LEN + t0 + trow)*D_MODEL + d0 + dcol;
        Afin[r] = f2bf(tb[dcol][trow] * gate[r]);
    }
}

// ---------------------------------------------------------------------------
extern "C" void kernel_launch(void* const* d_in, const int* in_sizes, int n_in,
                              void* d_out, int out_size, void* d_ws, size_t ws_size,
                              hipStream_t stream)
{
    (void)in_sizes; (void)n_in; (void)out_size; (void)ws_size;
    const float* u      = (const float*)d_in[0];
    const float* z      = (const float*)d_in[1];
    const float* fin_W  = (const float*)d_in[2];
    const float* fin_b  = (const float*)d_in[3];
    const float* freq   = (const float*)d_in[4];
    const float* mid_W  = (const float*)d_in[5];
    const float* mid_b  = (const float*)d_in[6];
    const float* fout_W = (const float*)d_in[7];
    const float* proj_W = (const float*)d_in[8];
    const float* proj_b = (const float*)d_in[9];
    const float* conv_W = (const float*)d_in[10];
    const float* conv_b = (const float*)d_in[11];
    const float* fbias  = (const float*)d_in[12];
    const float* out_W  = (const float*)d_in[13];
    const float* out_b  = (const float*)d_in[14];
    float* out = (float*)d_out;

    // ws layout (floats): hT | up | seqR | gateR   (total 66.05M f = 264 MB)
    float* ws    = (float*)d_ws;
    float* hT    = ws;                                   //  3,145,728 f
    float* up    = hT   + (size_t)D_MODEL*MAX_LEN;       // 37,748,736 f
    float* seqR  = up   + (size_t)ROWS*D3;               // 12,582,912 f
    float* gateR = seqR + (size_t)NBATCH*D_MODEL*MAX_LEN;// 12,582,912 f
    // aliases in regions dead at time of use:
    u16* Abf    = (u16*)seqR;                 // u bf16 (dead after GEMM1)
    u16* BpT1   = (u16*)gateR;                // proj_W^T bf16 (dead after GEMM1)
    u16* Afinbf = (u16*)up;                   // up fp32 dead after convprep
    u16* BpT2   = (u16*)(up + (size_t)20*1024*1024);  // out_W^T bf16, dead up region
    float* hTt  = up + (size_t)32*1024*1024;  // t-major h (dead before GEMM1 writes up)
    float* seqT = seqR;
    float* gate = gateR;

    filter_kernel<<<MAX_LEN, MLP_W, 0, stream>>>(z, fin_W, fin_b, freq,
                                                 mid_W, mid_b, fout_W, hTt);
    transpose_f32_kernel<<<dim3(D_MODEL/64, MAX_LEN/64), 256, 0, stream>>>(
        hTt, hT, MAX_LEN, D_MODEL);
    cast_bf16_kernel<<<(ROWS*D_MODEL)/(256*8), 256, 0, stream>>>(u, Abf, ROWS*D_MODEL);
    transpose_cast_kernel<<<dim3(D3/64, D_MODEL/64), 256, 0, stream>>>(
        proj_W, BpT1, D_MODEL, D3);
    gemm_mfma_kernel<<<dim3(D3/128, ROWS/128), 256, 0, stream>>>(
        Abf, BpT1, proj_b, up, ROWS, D3, D_MODEL);
    convprep_kernel<<<dim3(D_MODEL/64, MAX_LEN/64, NBATCH), 256, 0, stream>>>(
        up, conv_W, conv_b, seqT, gate);
    transpose_cast_kernel<<<dim3(D_MODEL/64, D_MODEL/64), 256, 0, stream>>>(
        out_W, BpT2, D_MODEL, D_MODEL);
    longconv_mfma_kernel<<<NBATCH*D_MODEL, 256, 0, stream>>>(seqT, hT, fbias);
    gatemul_kernel<<<dim3(D_MODEL/64, MAX_LEN/64, NBATCH), 256, 0, stream>>>(
        seqT, gate, Afinbf);
    gemm_mfma_kernel<<<dim3(D_MODEL/128, ROWS/128), 256, 0, stream>>>(
        Afinbf, BpT2, out_b, out, ROWS, D_MODEL, D_MODEL);
}

// Round 6
// 607.234 us; speedup vs baseline: 3.2834x; 1.0209x over previous
//
#include <hip/hip_runtime.h>
#include <math.h>

#define MAX_LEN 4096
#define D_MODEL 768
#define PE_DIM 65
#define MLP_W 64
#define NBATCH 4
#define D3 2304               // (ORDER+1)*D_MODEL
#define ROWS (NBATCH*MAX_LEN) // 16384

typedef unsigned short u16;
typedef unsigned int u32;
typedef float f4 __attribute__((ext_vector_type(4)));
typedef __bf16 bf16x8 __attribute__((ext_vector_type(8)));
typedef float f32x4 __attribute__((ext_vector_type(4)));

__device__ inline u16 f2bf(float x) {
    u32 u = __float_as_uint(x);
    u += 0x7fffu + ((u >> 16) & 1u);   // round-to-nearest-even
    return (u16)(u >> 16);
}
__device__ inline float bf2f(u16 v) { return __uint_as_float((u32)v << 16); }
__device__ inline u32 pk2(float a, float b) {
    return (u32)f2bf(a) | ((u32)f2bf(b) << 16);
}

// direct global->LDS async copy, 16B per lane; lds base must be wave-uniform.
// One call moves 64 lanes x 16B = 1KB, landing at ldsbase + lane*16B.
#define GLDS16(gp, lp) __builtin_amdgcn_global_load_lds( \
    (const __attribute__((address_space(1))) u32*)(gp), \
    (__attribute__((address_space(3))) u32*)(lp), 16, 0, 0)

// ---------------------------------------------------------------------------
// K1: filter MLP + decay -> hTt (MAX_LEN x D_MODEL, t-major, coalesced writes)
// ---------------------------------------------------------------------------
__global__ void filter_kernel(const float* __restrict__ z,
                              const float* __restrict__ fin_W,
                              const float* __restrict__ fin_b,
                              const float* __restrict__ freq,
                              const float* __restrict__ mid_W,
                              const float* __restrict__ mid_b,
                              const float* __restrict__ fout_W,
                              float* __restrict__ hTt)
{
    int t = blockIdx.x;
    int j = threadIdx.x;  // 0..63
    __shared__ float zrow[PE_DIM];
    __shared__ float k1[MLP_W];
    __shared__ float k2[MLP_W];
    __shared__ float k3[MLP_W];
    for (int i = j; i < PE_DIM; i += MLP_W) zrow[i] = z[t*PE_DIM + i];
    __syncthreads();
    float fj = freq[j];
    float acc = fin_b[j];
    for (int i = 0; i < PE_DIM; ++i) acc += zrow[i]*fin_W[i*MLP_W + j];
    k1[j] = sinf(fj*acc);
    __syncthreads();
    acc = mid_b[j];
    for (int i = 0; i < MLP_W; ++i) acc += k1[i]*mid_W[i*MLP_W + j];
    k2[j] = sinf(fj*acc);
    __syncthreads();
    acc = mid_b[MLP_W + j];
    for (int i = 0; i < MLP_W; ++i) acc += k2[i]*mid_W[MLP_W*MLP_W + i*MLP_W + j];
    k3[j] = sinf(fj*acc);
    __syncthreads();
    const float MIND = -3.0701134573253944f;   // ln(0.01)/1.5
    const float MAXD = -15.350567286626972f;   // ln(0.01)/0.3
    float tt = (float)t * (1.0f/(float)(MAX_LEN-1));
    for (int m = 0; m < D_MODEL/MLP_W; ++m) {
        int d = j + MLP_W*m;
        float a = 0.f;
        for (int i = 0; i < MLP_W; ++i) a += k3[i]*fout_W[i*D_MODEL + d];
        float delta = MIND + (MAXD-MIND)*((float)d*(1.0f/(float)(D_MODEL-1)));
        float dec = expf(-tt*fabsf(delta));
        hTt[(size_t)t*D_MODEL + d] = a*dec;   // coalesced
    }
}

// ---------------------------------------------------------------------------
// cast fp32 -> bf16 (elementwise, 8/thread)
// ---------------------------------------------------------------------------
__global__ void cast_bf16_kernel(const float* __restrict__ src,
                                 u16* __restrict__ dst, int n)
{
    int i = (blockIdx.x*256 + threadIdx.x)*8;
    if (i + 7 >= n) {
        for (int j = i; j < n; ++j) dst[j] = f2bf(src[j]);
        return;
    }
    float4 a = *(const float4*)(src + i);
    float4 b = *(const float4*)(src + i + 4);
    uint4 o;
    o.x = pk2(a.x, a.y);
    o.y = pk2(a.z, a.w);
    o.z = pk2(b.x, b.y);
    o.w = pk2(b.z, b.w);
    *(uint4*)(dst + i) = o;
}

// ---------------------------------------------------------------------------
// transpose + cast: src (R x C fp32) -> dst (C x R bf16)
// ---------------------------------------------------------------------------
__global__ void transpose_cast_kernel(const float* __restrict__ src,
                                      u16* __restrict__ dst, int R, int C)
{
    __shared__ u16 tile[64][65];
    int c0 = blockIdx.x*64, r0 = blockIdx.y*64;
    int tid = threadIdx.x;
    #pragma unroll
    for (int p = 0; p < 16; ++p) {
        int idx = tid + 256*p;
        int rr = idx >> 6, cc = idx & 63;
        tile[rr][cc] = f2bf(src[(size_t)(r0+rr)*C + c0 + cc]);
    }
    __syncthreads();
    #pragma unroll
    for (int p = 0; p < 16; ++p) {
        int idx = tid + 256*p;
        int cr = idx >> 6, rc = idx & 63;
        dst[(size_t)(c0+cr)*R + r0 + rc] = tile[rc][cr];
    }
}

// ---------------------------------------------------------------------------
// K2/K6: C[M,N] = A[M,K]bf16 @ Bt[N,K]bf16 + bias
// m97 structure: 128x128 tile, BK=32, global_load_lds width=16, unpadded
// 32-u16 LDS rows, 2 barriers/iter, 4x4 MFMA 16x16x32 per wave.
// Staging: wave w owns rows [w*32, w*32+32); one GLDS16 = 16 rows (1KB),
// so TWO calls per operand per wave (rows +0..15 and +16..31).
// ---------------------------------------------------------------------------
__launch_bounds__(256)
__global__ void gemm_mfma_kernel(const u16* __restrict__ A,   // M x K
                                 const u16* __restrict__ Bt,  // N x K
                                 const float* __restrict__ bias,
                                 float* __restrict__ C,
                                 int M, int N, int K)
{
    __shared__ __align__(16) u16 As[128*32];
    __shared__ __align__(16) u16 Bs[128*32];
    int tid = threadIdx.x;
    int lane = tid & 63, w = tid >> 6;
    int wm = (w >> 1)*64, wn = (w & 1)*64;
    int lrow = lane & 15, lch = lane >> 4;
    int m0 = blockIdx.y * 128, n0 = blockIdx.x * 128;

    // lane l -> row base w*32 + (l>>2) (0..15), col (l&3)*8 u16; lane landing
    // in LDS is base + l*8 u16 = (l>>2)*32 + (l&3)*8  (row-major 32-u16 rows).
    int srow = lane >> 2;          // 0..15
    int scol = (lane & 3)*8;
    const u16* Ag = A  + (size_t)(m0 + w*32 + srow)*K + scol;
    const u16* Bg = Bt + (size_t)(n0 + w*32 + srow)*K + scol;
    u16* AsW = As + w*1024;   // wave-uniform
    u16* BsW = Bs + w*1024;

    f32x4 acc[4][4];
    #pragma unroll
    for (int i = 0; i < 4; ++i)
        #pragma unroll
        for (int j = 0; j < 4; ++j)
            acc[i][j] = (f32x4){0.f,0.f,0.f,0.f};

    for (int k0 = 0; k0 < K; k0 += 32) {
        GLDS16(Ag + k0,            AsW);
        GLDS16(Ag + 16*(size_t)K + k0, AsW + 512);
        GLDS16(Bg + k0,            BsW);
        GLDS16(Bg + 16*(size_t)K + k0, BsW + 512);
        __syncthreads();               // drains vmcnt(0): tile visible
        bf16x8 af[4], bfr[4];
        #pragma unroll
        for (int i = 0; i < 4; ++i) {
            af[i]  = *(const bf16x8*)&As[(wm + i*16 + lrow)*32 + lch*8];
            bfr[i] = *(const bf16x8*)&Bs[(wn + i*16 + lrow)*32 + lch*8];
        }
        #pragma unroll
        for (int mt = 0; mt < 4; ++mt)
            #pragma unroll
            for (int nt = 0; nt < 4; ++nt)
                acc[mt][nt] = __builtin_amdgcn_mfma_f32_16x16x32_bf16(
                    af[mt], bfr[nt], acc[mt][nt], 0, 0, 0);
        __syncthreads();               // reads done before next overwrite
    }
    #pragma unroll
    for (int nt = 0; nt < 4; ++nt) {
        int n = n0 + wn + nt*16 + lrow;
        float bv = bias[n];
        #pragma unroll
        for (int mt = 0; mt < 4; ++mt) {
            int m = m0 + wm + mt*16 + lch*4;
            #pragma unroll
            for (int r = 0; r < 4; ++r)
                C[(size_t)(m + r)*N + n] = acc[mt][nt][r] + bv;
        }
    }
}

// ---------------------------------------------------------------------------
// K3: short conv (width 3, causal) + split; seq=x0*v -> bf16 (B,768,L),
// gate=x1 -> fp32 (B*L,768)
// ---------------------------------------------------------------------------
__global__ void convprep_kernel(const float* __restrict__ up,
                                const float* __restrict__ conv_W,
                                const float* __restrict__ conv_b,
                                u16* __restrict__ seqbf,
                                float* __restrict__ gate)
{
    __shared__ float sb[64][65];
    int d0 = blockIdx.x * 64;
    int t0 = blockIdx.y * 64;
    int b  = blockIdx.z;
    int tid = threadIdx.x;
    #pragma unroll
    for (int i = 0; i < 16; ++i) {
        int idx = tid + 256*i;
        int trow = idx >> 6, dcol = idx & 63;
        int t = t0 + trow;
        int d = d0 + dcol;
        size_t r = ((size_t)b*MAX_LEN + t)*D3;
        float uc[3];
        #pragma unroll
        for (int g = 0; g < 3; ++g) {
            int c = d + g*D_MODEL;
            float u0 = up[r + c];
            float u1 = (t >= 1) ? up[r - D3 + c]   : 0.f;
            float u2 = (t >= 2) ? up[r - 2*D3 + c] : 0.f;
            uc[g] = conv_W[c]*u2 + conv_W[D3 + c]*u1 + conv_W[2*D3 + c]*u0 + conv_b[c];
        }
        sb[trow][dcol] = uc[0]*uc[2];
        gate[((size_t)b*MAX_LEN + t)*D_MODEL + d] = uc[1];
    }
    __syncthreads();
    #pragma unroll
    for (int i = 0; i < 16; ++i) {
        int idx = tid + 256*i;
        int drow = idx >> 6, tcol = idx & 63;
        seqbf[((size_t)b*D_MODEL + d0 + drow)*MAX_LEN + t0 + tcol] = f2bf(sb[tcol][drow]);
    }
}

// ---------------------------------------------------------------------------
// K4: long causal depthwise conv via block-Toeplitz MFMA, one block per (b,d).
// Inputs bf16 (seqbf, hbf) -> staging is pure 16B copies. Output yT fp32.
// ---------------------------------------------------------------------------
__launch_bounds__(256)
__global__ void longconv_mfma_kernel(const u16* __restrict__ seqbf, // (B,768,L) bf16
                                     const u16* __restrict__ hbf,   // (768,L) bf16
                                     const float* __restrict__ filt_bias,
                                     float* __restrict__ yT)        // (B,768,L) fp32
{
    __shared__ __align__(16) u16 sq[4896];    // swizzled bf16 seq, 256-elem zero pad below
    __shared__ __align__(16) u16 hp[4112];    // bf16 h, 16-elem zero pad below
    __shared__ __align__(16) u16 A_s[8*640];  // 8 slabs, 16 rows x 40 u16 (32 + pad)

    int bd  = blockIdx.x;
    int d   = bd % D_MODEL;
    int tid = threadIdx.x;
    int lane = tid & 63, w = tid >> 6;
    int lrow = lane & 15, lch = lane >> 4;    // n (or i), quad

    const u16* srcb = seqbf + (size_t)bd*MAX_LEN;
    for (int q = tid; q < 544; q += 256) {          // logical 16B-quads: 32 pad + 512 data
        int p = ((q + (q >> 3)) << 3);              // physical u16 index
        uint4 o = make_uint4(0u, 0u, 0u, 0u);
        if (q >= 32) o = *(const uint4*)&srcb[(q-32)*8];
        *(uint4*)&sq[p] = o;
    }
    const u16* hsrcb = hbf + (size_t)d*MAX_LEN;
    for (int q = tid; q < 514; q += 256) {          // 2 pad quads + 512 data
        uint4 o = make_uint4(0u, 0u, 0u, 0u);
        if (q >= 2) o = *(const uint4*)&hsrcb[(q-2)*8];
        *(uint4*)&hp[q*8] = o;
    }

    f32x4 acc[4];
    #pragma unroll
    for (int g4 = 0; g4 < 4; ++g4) acc[g4] = (f32x4){0.f,0.f,0.f,0.f};

    // A-build assignment: tid = slab(3) | half(1) | i(4)
    int slab_b = tid >> 5;
    int half_b = (tid >> 4) & 1;
    int i_b    = tid & 15;
    u32* bld = (u32*)&A_s[slab_b*640 + i_b*40 + half_b*16];

    for (int r = 0; r < 16; ++r) {
        __syncthreads();   // prior round's MFMA reads done (and staging on r=0)
        // build 8 Toeplitz slabs: A[i][k] = hp[32 + 256r + 32*slab + i - k]
        {
            int hbase = 32 + 256*r + 32*slab_b + i_b - half_b*16;
            #pragma unroll
            for (int kk2 = 0; kk2 < 8; ++kk2) {
                u16 v0 = hp[hbase - 2*kk2];
                u16 v1 = hp[hbase - 2*kk2 - 1];
                bld[kk2] = (u32)v0 | ((u32)v1 << 16);
            }
        }
        __syncthreads();
        bf16x8 afr[8];
        #pragma unroll
        for (int s = 0; s < 8; ++s)
            afr[s] = *(const bf16x8*)&A_s[s*640 + lrow*40 + lch*8];
        #pragma unroll
        for (int g4 = 0; g4 < 4; ++g4) {
            int g = w + 4*g4;
            if (g < r) continue;                    // wave-uniform skip
            int ebase = 256 + 256*(g - r) - 16 + 16*lrow + 8*lch;
            #pragma unroll
            for (int s = 0; s < 8; ++s) {
                int elem = ebase - 32*s;            // multiple of 8
                int Q = elem >> 3;
                const bf16x8 bfr = *(const bf16x8*)&sq[(Q + (Q >> 3)) << 3];
                acc[g4] = __builtin_amdgcn_mfma_f32_16x16x32_bf16(
                    afr[s], bfr, acc[g4], 0, 0, 0);
            }
        }
    }
    __syncthreads();

    // epilogue: y = acc + filt_bias[d]*seq ; write fp32 to yT
    float fb = filt_bias[d];
    float* dsty = yT + (size_t)bd*MAX_LEN;
    #pragma unroll
    for (int g4 = 0; g4 < 4; ++g4) {
        int g = w + 4*g4;
        int t0 = 256*g + 16*lrow + 4*lch;
        f4 o;
        #pragma unroll
        for (int r4 = 0; r4 < 4; ++r4) {
            int elem = 256 + t0 + r4;
            int Q = elem >> 3;
            float sv = bf2f(sq[(((Q + (Q >> 3)) << 3)) | (elem & 7)]);
            o[r4] = acc[g4][r4] + fb*sv;
        }
        *(f4*)&dsty[t0] = o;
    }
}

// ---------------------------------------------------------------------------
// K5: Afin(bf16)[b*L+t, d] = yT[b,d,t] * gate[b*L+t, d]
// ---------------------------------------------------------------------------
__global__ void gatemul_kernel(const float* __restrict__ yT,
                               const float* __restrict__ gate,
                               u16* __restrict__ Afin)
{
    __shared__ float tb[64][65];
    int d0 = blockIdx.x * 64;
    int t0 = blockIdx.y * 64;
    int b  = blockIdx.z;
    int tid = threadIdx.x;
    #pragma unroll
    for (int i = 0; i < 16; ++i) {
        int idx = tid + 256*i;
        int drow = idx >> 6, tcol = idx & 63;
        tb[drow][tcol] = yT[((size_t)b*D_MODEL + d0 + drow)*MAX_LEN + t0 + tcol];
    }
    __syncthreads();
    #pragma unroll
    for (int i = 0; i < 16; ++i) {
        int idx = tid + 256*i;
        int trow = idx >> 6, dcol = idx & 63;
        size_t r = ((size_t)b*MAX_LEN + t0 + trow)*D_MODEL + d0 + dcol;
        Afin[r] = f2bf(tb[dcol][trow] * gate[r]);
    }
}

// ---------------------------------------------------------------------------
extern "C" void kernel_launch(void* const* d_in, const int* in_sizes, int n_in,
                              void* d_out, int out_size, void* d_ws, size_t ws_size,
                              hipStream_t stream)
{
    (void)in_sizes; (void)n_in; (void)out_size; (void)ws_size;
    const float* u      = (const float*)d_in[0];
    const float* z      = (const float*)d_in[1];
    const float* fin_W  = (const float*)d_in[2];
    const float* fin_b  = (const float*)d_in[3];
    const float* freq   = (const float*)d_in[4];
    const float* mid_W  = (const float*)d_in[5];
    const float* mid_b  = (const float*)d_in[6];
    const float* fout_W = (const float*)d_in[7];
    const float* proj_W = (const float*)d_in[8];
    const float* proj_b = (const float*)d_in[9];
    const float* conv_W = (const float*)d_in[10];
    const float* conv_b = (const float*)d_in[11];
    const float* fbias  = (const float*)d_in[12];
    const float* out_W  = (const float*)d_in[13];
    const float* out_b  = (const float*)d_in[14];
    float* out = (float*)d_out;

    // ws layout (floats), total 65,667,072 f = 262.7 MB:
    float* ws    = (float*)d_ws;
    u16*   hbf   = (u16*)ws;                          // 3,145,728 u16 = 1,572,864 f
    float* up    = ws + 1572864;                      // 37,748,736 f
    float* gate  = up + 37748736;                     // 12,582,912 f
    u16*   seqbf = (u16*)(gate + 12582912);           // 12,582,912 u16 = 6,291,456 f
    u16*   Abf   = (u16*)(gate + 12582912 + 6291456); // 12,582,912 u16 = 6,291,456 f
    u16*   BpT1  = (u16*)(gate + 12582912 + 2*6291456);          // 884,736 f
    u16*   BpT2  = (u16*)(gate + 12582912 + 2*6291456 + 884736); // 294,912 f
    // aliases in regions dead at time of use:
    float* hTt   = up;                    // t-major h; dead before GEMM1 writes up
    float* yT    = up;                    // longconv out; up fp32 dead after convprep
    u16*   Afinbf= (u16*)(up + 16777216); // gatemul out; disjoint from yT (12.58M f)

    filter_kernel<<<MAX_LEN, MLP_W, 0, stream>>>(z, fin_W, fin_b, freq,
                                                 mid_W, mid_b, fout_W, hTt);
    transpose_cast_kernel<<<dim3(D_MODEL/64, MAX_LEN/64), 256, 0, stream>>>(
        hTt, hbf, MAX_LEN, D_MODEL);
    cast_bf16_kernel<<<(ROWS*D_MODEL)/(256*8), 256, 0, stream>>>(u, Abf, ROWS*D_MODEL);
    transpose_cast_kernel<<<dim3(D3/64, D_MODEL/64), 256, 0, stream>>>(
        proj_W, BpT1, D_MODEL, D3);
    gemm_mfma_kernel<<<dim3(D3/128, ROWS/128), 256, 0, stream>>>(
        Abf, BpT1, proj_b, up, ROWS, D3, D_MODEL);
    convprep_kernel<<<dim3(D_MODEL/64, MAX_LEN/64, NBATCH), 256, 0, stream>>>(
        up, conv_W, conv_b, seqbf, gate);
    transpose_cast_kernel<<<dim3(D_MODEL/64, D_MODEL/64), 256, 0, stream>>>(
        out_W, BpT2, D_MODEL, D_MODEL);
    longconv_mfma_kernel<<<NBATCH*D_MODEL, 256, 0, stream>>>(seqbf, hbf, fbias, yT);
    gatemul_kernel<<<dim3(D_MODEL/64, MAX_LEN/64, NBATCH), 256, 0, stream>>>(
        yT, gate, Afinbf);
    gemm_mfma_kernel<<<dim3(D_MODEL/128, ROWS/128), 256, 0, stream>>>(
        Afinbf, BpT2, out_b, out, ROWS, D_MODEL, D_MODEL);
}